// Round 7
// baseline (360.886 us; speedup 1.0000x reference)
//
#include <hip/hip_runtime.h>
#include <hip/hip_bf16.h>

#define EPSV 1e-5f

typedef unsigned short u16;
typedef __attribute__((ext_vector_type(8))) short short8;
typedef __attribute__((ext_vector_type(4))) float f32x4;
typedef __hip_bfloat16 bf16;

__device__ __forceinline__ unsigned int pack2(float a, float b) {
  bf16 ha = __float2bfloat16(a), hb = __float2bfloat16(b);
  u16 ua, ub;
  __builtin_memcpy(&ua, &ha, 2);
  __builtin_memcpy(&ub, &hb, 2);
  return (unsigned int)ua | ((unsigned int)ub << 16);
}

// ============================================================================
// FAST PATH (MFMA) — position-major intermediates [M=6272, C]
// ============================================================================

// ---- transpose-convert lut [K,N] fp32 -> lutT [N,K] bf16 ----
template<int K, int N>
__global__ __launch_bounds__(256) void lutT_kernel(const float* __restrict__ in,
                                                   bf16* __restrict__ out)
{
  __shared__ float t[64][65];
  const int bk = blockIdx.x % (K / 64), bn = blockIdx.x / (K / 64);
  const int k0 = bk * 64, n0 = bn * 64;
  for (int idx = threadIdx.x; idx < 4096; idx += 256) {
    int r = idx >> 6, c = idx & 63;
    t[r][c] = in[(size_t)(k0 + r) * N + n0 + c];
  }
  __syncthreads();
  for (int idx = threadIdx.x; idx < 4096; idx += 256) {
    int r = idx >> 6, c = idx & 63;
    out[(size_t)(n0 + r) * K + k0 + c] = __float2bfloat16(t[c][r]);
  }
}

// ---- transpose x [B,1024,196] -> xT [6272,1024] fp32 ----
__global__ __launch_bounds__(256) void xT_kernel(const float* __restrict__ x,
                                                 float* __restrict__ xT)
{
  __shared__ float t[64 * 199];
  const int b = blockIdx.x >> 4, c0 = (blockIdx.x & 15) * 64;
  for (int idx = threadIdx.x; idx < 64 * 196; idx += 256) {
    int ci = idx / 196, p = idx - ci * 196;
    t[ci * 199 + p] = x[(size_t)(b * 1024 + c0 + ci) * 196 + p];
  }
  __syncthreads();
  for (int idx = threadIdx.x; idx < 196 * 64; idx += 256) {
    int p = idx >> 6, ci = idx & 63;
    xT[(size_t)(b * 196 + p) * 1024 + c0 + ci] = t[ci * 199 + p];
  }
}

// ---- attn layer 1: xT [M,1024] -> attn bf16 [M,4096] ----
// block = (row of 14 pos) x (group of 32 codebooks); 3584 blocks.
// thread = codebook (32) x pos-slot (8); <=2 positions/thread.
__global__ __launch_bounds__(256) void attn1_kernel(const float* __restrict__ xT,
    const float* __restrict__ cent, const float* __restrict__ invt,
    u16* __restrict__ attn)
{
  __shared__ float vs[14 * 128];     // 7 KB: [pos][chan_local]
  __shared__ float cs[32 * 68];      // 8.5 KB: [cb][k*4+j]
  const int tid = threadIdx.x;
  const int row = blockIdx.x >> 3, cg = blockIdx.x & 7;
  const int m0 = row * 14;
  for (int idx = tid; idx < 448; idx += 256) {
    int p = idx >> 5, c4 = idx & 31;
    *(float4*)&vs[p * 128 + c4 * 4] =
        *(const float4*)&xT[(size_t)(m0 + p) * 1024 + cg * 128 + c4 * 4];
  }
  for (int idx = tid; idx < 512; idx += 256) {
    int cb = idx >> 4, kk = idx & 15;
    *(float4*)&cs[cb * 68 + kk * 4] =
        *(const float4*)&cent[(size_t)(cg * 32 + cb) * 64 + kk * 4];
  }
  __syncthreads();
  const float it = invt[0];
  const int cb = tid & 31, pq = tid >> 5;      // pq 0..7, wave-uniform halves
  const int np = (pq < 6) ? 2 : 1;             // p = i*8 + pq < 14
  float4 v[2];
  v[0] = *(const float4*)&vs[pq * 128 + cb * 4];
  if (np > 1) v[1] = *(const float4*)&vs[(8 + pq) * 128 + cb * 4];
  float s[2][16];
  #pragma unroll
  for (int k = 0; k < 16; k++) {
    const float4 c = *(const float4*)&cs[cb * 68 + k * 4];
    const float cn = c.x * c.x + c.y * c.y + c.z * c.z + c.w * c.w;
    #pragma unroll
    for (int i = 0; i < 2; i++) if (i < np) {
      float d = v[i].x * c.x + v[i].y * c.y + v[i].z * c.z + v[i].w * c.w;
      s[i][k] = it * (2.f * d - cn);
    }
  }
  #pragma unroll
  for (int i = 0; i < 2; i++) if (i < np) {
    float mx = -3e38f;
    #pragma unroll
    for (int k = 0; k < 16; k++) mx = fmaxf(mx, s[i][k]);
    float sum = 0.f;
    #pragma unroll
    for (int k = 0; k < 16; k++) { float e = __expf(s[i][k] - mx); s[i][k] = e; sum += e; }
    const float r = 1.f / sum;
    uint4 w0, w1;
    w0.x = pack2(s[i][0] * r,  s[i][1] * r);  w0.y = pack2(s[i][2] * r,  s[i][3] * r);
    w0.z = pack2(s[i][4] * r,  s[i][5] * r);  w0.w = pack2(s[i][6] * r,  s[i][7] * r);
    w1.x = pack2(s[i][8] * r,  s[i][9] * r);  w1.y = pack2(s[i][10] * r, s[i][11] * r);
    w1.z = pack2(s[i][12] * r, s[i][13] * r); w1.w = pack2(s[i][14] * r, s[i][15] * r);
    uint4* dst = (uint4*)(attn + (size_t)(m0 + i * 8 + pq) * 4096 + (cg * 32 + cb) * 16);
    dst[0] = w0; dst[1] = w1;
  }
}

// ---- attn layer 2 (3x3): out1 [M,256] + bn1 -> attn bf16 [M,4096] ----
// Same 32-cb split: 3584 blocks, 24.7 KB LDS -> 6 blocks/CU.
__global__ __launch_bounds__(256) void attn2_kernel(const float* __restrict__ out1,
    const float* __restrict__ ss, const float* __restrict__ cent,
    const float* __restrict__ invt, u16* __restrict__ attn)
{
  __shared__ float vs[3 * 16 * 32];  // 6 KB: [dy][x1][c], x1 cols 0,15 = zero pad
  __shared__ float cs[32 * 145];     // 18.1 KB: [cb][k*9+j]
  const int tid = threadIdx.x;
  const int row = blockIdx.x >> 3, cg = blockIdx.x & 7;
  const int b = row / 14, y = row % 14, m0 = row * 14;
  for (int e = tid; e < 1536; e += 256) {
    int c = e & 31, x1 = (e >> 5) & 15, dy = e >> 9;
    int yy = y + dy - 1, xx = x1 - 1;
    float v = 0.f;
    int ch = cg * 32 + c;
    if (yy >= 0 && yy < 14 && xx >= 0 && xx < 14) {
      float val = out1[(size_t)((b * 14 + yy) * 14 + xx) * 256 + ch];
      v = fmaxf(val * ss[ch] + ss[256 + ch], 0.f);   // pad AFTER bn+relu
    }
    vs[e] = v;
  }
  for (int idx = tid; idx < 4608; idx += 256) {
    int cb = idx / 144, r = idx - cb * 144;
    cs[cb * 145 + r] = cent[(size_t)cg * 4608 + idx];
  }
  __syncthreads();
  const float it = invt[0];
  const int cb = tid & 31, pq = tid >> 5;
  const int np = (pq < 6) ? 2 : 1;
  float v[2][9];
  #pragma unroll
  for (int i = 0; i < 2; i++) if (i < np) {
    const int x = i * 8 + pq;
    #pragma unroll
    for (int dy = 0; dy < 3; dy++)
      #pragma unroll
      for (int dx = 0; dx < 3; dx++)
        v[i][dy * 3 + dx] = vs[(dy * 16 + x + dx) * 32 + cb];
  }
  float s[2][16];
  #pragma unroll
  for (int k = 0; k < 16; k++) {
    float c9[9], cn = 0.f;
    #pragma unroll
    for (int j = 0; j < 9; j++) { c9[j] = cs[cb * 145 + k * 9 + j]; cn = fmaf(c9[j], c9[j], cn); }
    #pragma unroll
    for (int i = 0; i < 2; i++) if (i < np) {
      float d = 0.f;
      #pragma unroll
      for (int j = 0; j < 9; j++) d = fmaf(c9[j], v[i][j], d);
      s[i][k] = it * (2.f * d - cn);
    }
  }
  #pragma unroll
  for (int i = 0; i < 2; i++) if (i < np) {
    float mx = -3e38f;
    #pragma unroll
    for (int k = 0; k < 16; k++) mx = fmaxf(mx, s[i][k]);
    float sum = 0.f;
    #pragma unroll
    for (int k = 0; k < 16; k++) { float e = __expf(s[i][k] - mx); s[i][k] = e; sum += e; }
    const float r = 1.f / sum;
    uint4 w0, w1;
    w0.x = pack2(s[i][0] * r,  s[i][1] * r);  w0.y = pack2(s[i][2] * r,  s[i][3] * r);
    w0.z = pack2(s[i][4] * r,  s[i][5] * r);  w0.w = pack2(s[i][6] * r,  s[i][7] * r);
    w1.x = pack2(s[i][8] * r,  s[i][9] * r);  w1.y = pack2(s[i][10] * r, s[i][11] * r);
    w1.z = pack2(s[i][12] * r, s[i][13] * r); w1.w = pack2(s[i][14] * r, s[i][15] * r);
    uint4* dst = (uint4*)(attn + (size_t)(m0 + i * 8 + pq) * 4096 + (cg * 32 + cb) * 16);
    dst[0] = w0; dst[1] = w1;
  }
}

// ---- attn layer 3 (R3-proven) ----
__global__ __launch_bounds__(256) void attn3_kernel(const float* __restrict__ out2,
    const float* __restrict__ ss, const float* __restrict__ cent,
    const float* __restrict__ invt, bf16* __restrict__ attn)
{
  const int t = threadIdx.x;
  const int cb = t & 63, ml = t >> 6;
  const int m0 = blockIdx.x * 16;
  const float it = invt[0];
  float4 cv[16]; float cn[16];
  const float4* cc = (const float4*)(cent + cb * 64);
  #pragma unroll
  for (int k = 0; k < 16; k++) {
    cv[k] = cc[k];
    cn[k] = cv[k].x * cv[k].x + cv[k].y * cv[k].y + cv[k].z * cv[k].z + cv[k].w * cv[k].w;
  }
  const float4 scv = *(const float4*)(ss + cb * 4);
  const float4 shv = *(const float4*)(ss + 256 + cb * 4);
  for (int g = 0; g < 4; g++) {
    const int m = m0 + g * 4 + ml;
    float4 xv = *(const float4*)(out2 + (size_t)m * 256 + cb * 4);
    float4 v;
    v.x = fmaxf(xv.x * scv.x + shv.x, 0.f);
    v.y = fmaxf(xv.y * scv.y + shv.y, 0.f);
    v.z = fmaxf(xv.z * scv.z + shv.z, 0.f);
    v.w = fmaxf(xv.w * scv.w + shv.w, 0.f);
    float s[16], mx = -3e38f;
    #pragma unroll
    for (int k = 0; k < 16; k++) {
      float d = v.x * cv[k].x + v.y * cv[k].y + v.z * cv[k].z + v.w * cv[k].w;
      s[k] = it * (2.f * d - cn[k]);
      mx = fmaxf(mx, s[k]);
    }
    float sum = 0.f;
    #pragma unroll
    for (int k = 0; k < 16; k++) { float e = __expf(s[k] - mx); s[k] = e; sum += e; }
    float r = 1.f / sum;
    #pragma unroll
    for (int k = 0; k < 16; k++)
      attn[(size_t)m * 1024 + cb * 16 + k] = __float2bfloat16(s[k] * r);
  }
}

// ---- MFMA fragment compute on one 64x64 LDS tile pair ----
__device__ __forceinline__ void gemm_tile_compute(const u16* __restrict__ Abuf,
    const u16* __restrict__ Bbuf, int lane, int wm, int wn, f32x4 acc[2][2])
{
  #pragma unroll
  for (int ks = 0; ks < 2; ks++) {
    short8 a[2], b[2];
    #pragma unroll
    for (int f = 0; f < 2; f++) {
      const int ra = wm * 32 + f * 16 + (lane & 15);
      const int ja = (ks * 4 + (lane >> 4)) ^ (ra & 7);
      a[f] = *(const short8*)(Abuf + ra * 64 + ja * 8);
      const int rb = wn * 32 + f * 16 + (lane & 15);
      const int jb = (ks * 4 + (lane >> 4)) ^ (rb & 7);
      b[f] = *(const short8*)(Bbuf + rb * 64 + jb * 8);
    }
    #pragma unroll
    for (int fm = 0; fm < 2; fm++)
      #pragma unroll
      for (int fn = 0; fn < 2; fn++)
        acc[fm][fn] = __builtin_amdgcn_mfma_f32_16x16x32_bf16(a[fm], b[fn], acc[fm][fn], 0, 0, 0);
  }
}

// ---- bf16 MFMA GEMM (R6-proven): 64x64 tile, BK=64, dbuf LDS + reg prefetch,
//      optional split-K ----
template<int KDIM, int NTILES, int KSLICES>
__global__ __launch_bounds__(256) void gemm_kernel(const u16* __restrict__ A,
    const u16* __restrict__ Bt, float* __restrict__ C0, float* __restrict__ C1)
{
  constexpr int NDIM = NTILES * 64;
  __shared__ __align__(16) u16 Asm[2][64 * 64];
  __shared__ __align__(16) u16 Bsm[2][64 * 64];
  const int tid = threadIdx.x;
  const int nt = blockIdx.x % NTILES;
  const int mt = (blockIdx.x / NTILES) % 98;
  const int sl = blockIdx.x / (NTILES * 98);
  float* __restrict__ C = (KSLICES == 2 && sl == 1) ? C1 : C0;
  const int kbeg = sl * (KDIM / KSLICES), kend = kbeg + KDIM / KSLICES;
  const int m0 = mt * 64, n0 = nt * 64;
  const int lane = tid & 63;
  const int wm = (tid >> 7) & 1, wn = (tid >> 6) & 1;

  int rowi[2], jsi[2], jgi[2];
  #pragma unroll
  for (int i = 0; i < 2; i++) {
    const int L = tid + 256 * i;
    rowi[i] = L >> 3; jsi[i] = L & 7; jgi[i] = jsi[i] ^ (rowi[i] & 7);
  }

  f32x4 acc[2][2];
  const f32x4 zero = {0.f, 0.f, 0.f, 0.f};
  acc[0][0] = zero; acc[0][1] = zero; acc[1][0] = zero; acc[1][1] = zero;

  int4 av[2], bv[2];
  #pragma unroll
  for (int i = 0; i < 2; i++) {
    av[i] = *(const int4*)(A + (size_t)(m0 + rowi[i]) * KDIM + kbeg + jsi[i] * 8);
    bv[i] = *(const int4*)(Bt + (size_t)(n0 + rowi[i]) * KDIM + kbeg + jsi[i] * 8);
  }
  #pragma unroll
  for (int i = 0; i < 2; i++) {
    *(int4*)(&Asm[0][rowi[i] * 64 + jgi[i] * 8]) = av[i];
    *(int4*)(&Bsm[0][rowi[i] * 64 + jgi[i] * 8]) = bv[i];
  }
  __syncthreads();

  int cur = 0;
  for (int kb = kbeg + 64; kb < kend; kb += 64) {
    #pragma unroll
    for (int i = 0; i < 2; i++) {
      av[i] = *(const int4*)(A + (size_t)(m0 + rowi[i]) * KDIM + kb + jsi[i] * 8);
      bv[i] = *(const int4*)(Bt + (size_t)(n0 + rowi[i]) * KDIM + kb + jsi[i] * 8);
    }
    gemm_tile_compute(Asm[cur], Bsm[cur], lane, wm, wn, acc);
    #pragma unroll
    for (int i = 0; i < 2; i++) {
      *(int4*)(&Asm[cur ^ 1][rowi[i] * 64 + jgi[i] * 8]) = av[i];
      *(int4*)(&Bsm[cur ^ 1][rowi[i] * 64 + jgi[i] * 8]) = bv[i];
    }
    __syncthreads();
    cur ^= 1;
  }
  gemm_tile_compute(Asm[cur], Bsm[cur], lane, wm, wn, acc);

  #pragma unroll
  for (int fm = 0; fm < 2; fm++)
    #pragma unroll
    for (int fn = 0; fn < 2; fn++) {
      const int col = n0 + wn * 32 + fn * 16 + (lane & 15);
      const int rbase = m0 + wm * 32 + fm * 16 + (lane >> 4) * 4;
      #pragma unroll
      for (int r = 0; r < 4; r++)
        C[(size_t)(rbase + r) * NDIM + col] = acc[fm][fn][r];
    }
}

// ---- add partials: dst += src (1,605,632 floats as float4) ----
__global__ __launch_bounds__(256) void add_kernel(float* __restrict__ dst,
                                                  const float* __restrict__ src)
{
  const int idx = blockIdx.x * 256 + threadIdx.x;
  float4 a = ((const float4*)dst)[idx];
  float4 b = ((const float4*)src)[idx];
  a.x += b.x; a.y += b.y; a.z += b.z; a.w += b.w;
  ((float4*)dst)[idx] = a;
}

// ---- BN stats, stage 1: 64-row partial sums ----
template<int CH>
__global__ __launch_bounds__(256) void bnpart_kernel(const float* __restrict__ buf,
                                                     float* __restrict__ part)
{
  constexpr int PC = CH / 256;
  const int t = threadIdx.x, m0 = blockIdx.x * 64;
  float s[PC], s2[PC];
  #pragma unroll
  for (int j = 0; j < PC; j++) { s[j] = 0.f; s2[j] = 0.f; }
  for (int i = 0; i < 64; i++) {
    const float* row = buf + (size_t)(m0 + i) * CH;
    #pragma unroll
    for (int j = 0; j < PC; j++) {
      float v = row[t + j * 256];
      s[j] += v; s2[j] = fmaf(v, v, s2[j]);
    }
  }
  #pragma unroll
  for (int j = 0; j < PC; j++) {
    part[(size_t)blockIdx.x * (2 * CH) + t + j * 256] = s[j];
    part[(size_t)blockIdx.x * (2 * CH) + CH + t + j * 256] = s2[j];
  }
}

// ---- BN stats, stage 2 ----
template<int CH>
__global__ __launch_bounds__(256) void bnfin_kernel(const float* __restrict__ part,
    const float* __restrict__ g, const float* __restrict__ bb, float* __restrict__ ss)
{
  const int c = blockIdx.x * 256 + threadIdx.x;
  float S = 0.f, S2 = 0.f;
  for (int i = 0; i < 98; i++) {
    S += part[(size_t)i * (2 * CH) + c];
    S2 += part[(size_t)i * (2 * CH) + CH + c];
  }
  float mean = S * (1.f / 6272.f);
  float var = S2 * (1.f / 6272.f) - mean * mean;
  float sc = g[c] * rsqrtf(var + EPSV);
  ss[c] = sc;
  ss[CH + c] = bb[c] - mean * sc;
}

// ---- final: bn3 + transpose to channel-major + identity + relu ----
__global__ __launch_bounds__(256) void tfinal_kernel(const float* __restrict__ out3,
    const float* __restrict__ ss, const float* __restrict__ x, float* __restrict__ out)
{
  __shared__ float t[64 * 199];
  const int b = blockIdx.x >> 4, n0 = (blockIdx.x & 15) * 64;
  for (int idx = threadIdx.x; idx < 196 * 64; idx += 256) {
    int p = idx >> 6, ni = idx & 63;
    float v = out3[(size_t)(b * 196 + p) * 1024 + n0 + ni] * ss[n0 + ni] + ss[1024 + n0 + ni];
    t[ni * 199 + p] = v;
  }
  __syncthreads();
  for (int idx = threadIdx.x; idx < 64 * 196; idx += 256) {
    int ni = idx / 196, p = idx - ni * 196;
    size_t o = (size_t)(b * 1024 + n0 + ni) * 196 + p;
    out[o] = fmaxf(t[ni * 199 + p] + x[o], 0.f);
  }
}

// ============================================================================
// FALLBACK PATH (round-2 proven kernels, used only if ws_size is too small)
// ============================================================================

template<int CIN, int OUT, bool APPLY_BN>
__global__ __launch_bounds__(256) void amm1x1_kernel(
    const float* __restrict__ xin, const float* __restrict__ ss,
    const float* __restrict__ cent, const float* __restrict__ lut,
    const float* __restrict__ invt, float* __restrict__ outbuf)
{
  constexpr int NCB = CIN / 4;
  constexpr int NO = OUT / 256;
  __shared__ float vsm[CIN * 14];
  __shared__ __align__(16) float attn_sm[14 * 16];
  const int tid = threadIdx.x;
  const int b = blockIdx.x / 14, y = blockIdx.x % 14;
  const int rowbase = y * 14;
  for (int e = tid; e < CIN * 14; e += 256) {
    int c = e / 14, xc = e - c * 14;
    float v = xin[(b * CIN + c) * 196 + rowbase + xc];
    if (APPLY_BN) v = fmaxf(v * ss[c] + ss[CIN + c], 0.f);
    vsm[e] = v;
  }
  __syncthreads();
  float acc[14 * NO];
  #pragma unroll
  for (int i = 0; i < 14 * NO; i++) acc[i] = 0.f;
  const float it = invt[0];
  const int p_ = tid >> 4, k_ = tid & 15;
  for (int cb = 0; cb < NCB; ++cb) {
    if (tid < 224) {
      const float* cc = cent + (cb * 16 + k_) * 4;
      float s = 0.f;
      #pragma unroll
      for (int si = 0; si < 4; si++) {
        float cv = cc[si];
        float vv = vsm[(cb * 4 + si) * 14 + p_];
        s = fmaf(cv, 2.f * vv - cv, s);
      }
      s *= it;
      float m = s;
      #pragma unroll
      for (int off = 8; off; off >>= 1) m = fmaxf(m, __shfl_xor(m, off, 16));
      float e = __expf(s - m);
      float sum = e;
      #pragma unroll
      for (int off = 8; off; off >>= 1) sum += __shfl_xor(sum, off, 16);
      attn_sm[p_ * 16 + k_] = e / sum;
    }
    __syncthreads();
    float lv[NO][16];
    #pragma unroll
    for (int j = 0; j < NO; j++)
      #pragma unroll
      for (int k = 0; k < 16; k++)
        lv[j][k] = lut[(cb * 16 + k) * OUT + j * 256 + tid];
    const float4* a4 = (const float4*)attn_sm;
    #pragma unroll
    for (int p = 0; p < 14; p++) {
      float4 q0 = a4[p*4+0], q1 = a4[p*4+1], q2 = a4[p*4+2], q3 = a4[p*4+3];
      float av[16] = {q0.x,q0.y,q0.z,q0.w, q1.x,q1.y,q1.z,q1.w,
                      q2.x,q2.y,q2.z,q2.w, q3.x,q3.y,q3.z,q3.w};
      #pragma unroll
      for (int j = 0; j < NO; j++) {
        float s = acc[p * NO + j];
        #pragma unroll
        for (int k = 0; k < 16; k++) s = fmaf(av[k], lv[j][k], s);
        acc[p * NO + j] = s;
      }
    }
    __syncthreads();
  }
  #pragma unroll
  for (int j = 0; j < NO; j++) {
    int o = j * 256 + tid;
    #pragma unroll
    for (int p = 0; p < 14; p++)
      outbuf[(b * OUT + o) * 196 + rowbase + p] = acc[p * NO + j];
  }
}

__global__ __launch_bounds__(256) void amm3x3_kernel(
    const float* __restrict__ xin, const float* __restrict__ ss,
    const float* __restrict__ cent, const float* __restrict__ lut,
    const float* __restrict__ invt, float* __restrict__ outbuf)
{
  __shared__ float vsm[256 * 3 * 16];
  __shared__ __align__(16) float attn_sm[14 * 16];
  const int tid = threadIdx.x;
  const int b = blockIdx.x / 14, y = blockIdx.x % 14;
  for (int e = tid; e < 256 * 3 * 16; e += 256) {
    int c = e / 48, rem = e - c * 48, i = rem >> 4, col = rem & 15;
    int yy = y + i - 1, xx = col - 1;
    float v = 0.f;
    if (yy >= 0 && yy < 14 && xx >= 0 && xx < 14) {
      v = xin[(b * 256 + c) * 196 + yy * 14 + xx];
      v = fmaxf(v * ss[c] + ss[256 + c], 0.f);
    }
    vsm[e] = v;
  }
  __syncthreads();
  float acc[14];
  #pragma unroll
  for (int i = 0; i < 14; i++) acc[i] = 0.f;
  const float it = invt[0];
  const int p_ = tid >> 4, k_ = tid & 15;
  for (int cb = 0; cb < 256; ++cb) {
    if (tid < 224) {
      const float* cc = cent + (cb * 16 + k_) * 9;
      float s = 0.f;
      #pragma unroll
      for (int i = 0; i < 3; i++)
        #pragma unroll
        for (int j = 0; j < 3; j++) {
          float cv = cc[i * 3 + j];
          float vv = vsm[(cb * 3 + i) * 16 + p_ + j];
          s = fmaf(cv, 2.f * vv - cv, s);
        }
      s *= it;
      float m = s;
      #pragma unroll
      for (int off = 8; off; off >>= 1) m = fmaxf(m, __shfl_xor(m, off, 16));
      float e = __expf(s - m);
      float sum = e;
      #pragma unroll
      for (int off = 8; off; off >>= 1) sum += __shfl_xor(sum, off, 16);
      attn_sm[p_ * 16 + k_] = e / sum;
    }
    __syncthreads();
    float lv[16];
    #pragma unroll
    for (int k = 0; k < 16; k++) lv[k] = lut[(cb * 16 + k) * 256 + tid];
    const float4* a4 = (const float4*)attn_sm;
    #pragma unroll
    for (int p = 0; p < 14; p++) {
      float4 q0 = a4[p*4+0], q1 = a4[p*4+1], q2 = a4[p*4+2], q3 = a4[p*4+3];
      float av[16] = {q0.x,q0.y,q0.z,q0.w, q1.x,q1.y,q1.z,q1.w,
                      q2.x,q2.y,q2.z,q2.w, q3.x,q3.y,q3.z,q3.w};
      float s = acc[p];
      #pragma unroll
      for (int k = 0; k < 16; k++) s = fmaf(av[k], lv[k], s);
      acc[p] = s;
    }
    __syncthreads();
  }
  #pragma unroll
  for (int p = 0; p < 14; p++)
    outbuf[(b * 256 + tid) * 196 + y * 14 + p] = acc[p];
}

template<int CH>
__global__ __launch_bounds__(256) void bnstats_kernel(const float* __restrict__ buf,
    const float* __restrict__ g, const float* __restrict__ bb, float* __restrict__ ss)
{
  const int c = blockIdx.x, tid = threadIdx.x;
  float s = 0.f, s2 = 0.f;
  for (int e = tid; e < 32 * 196; e += 256) {
    int bi = e / 196, l = e - bi * 196;
    float v = buf[(bi * CH + c) * 196 + l];
    s += v; s2 = fmaf(v, v, s2);
  }
  #pragma unroll
  for (int off = 32; off; off >>= 1) { s += __shfl_down(s, off); s2 += __shfl_down(s2, off); }
  __shared__ float red[8];
  int w = tid >> 6;
  if ((tid & 63) == 0) { red[w] = s; red[4 + w] = s2; }
  __syncthreads();
  if (tid == 0) {
    float S  = red[0] + red[1] + red[2] + red[3];
    float S2 = red[4] + red[5] + red[6] + red[7];
    float mean = S * (1.f / 6272.f);
    float var  = S2 * (1.f / 6272.f) - mean * mean;
    float sc = g[c] * rsqrtf(var + EPSV);
    ss[c] = sc;
    ss[CH + c] = bb[c] - mean * sc;
  }
}

__global__ __launch_bounds__(256) void final_old_kernel(float* __restrict__ out3,
    const float* __restrict__ ss, const float* __restrict__ x)
{
  const int total = 32 * 1024 * 196;
  for (int idx = blockIdx.x * 256 + threadIdx.x; idx < total; idx += gridDim.x * 256) {
    int c = (idx / 196) & 1023;
    float v = out3[idx] * ss[c] + ss[1024 + c] + x[idx];
    out3[idx] = fmaxf(v, 0.f);
  }
}

// ============================================================================

extern "C" void kernel_launch(void* const* d_in, const int* in_sizes, int n_in,
                              void* d_out, int out_size, void* d_ws, size_t ws_size,
                              hipStream_t stream) {
  const float* x   = (const float*)d_in[0];
  const float* c1c = (const float*)d_in[1];
  const float* c1l = (const float*)d_in[2];
  const float* c1t = (const float*)d_in[3];
  const float* c2c = (const float*)d_in[4];
  const float* c2l = (const float*)d_in[5];
  const float* c2t = (const float*)d_in[6];
  const float* c3c = (const float*)d_in[7];
  const float* c3l = (const float*)d_in[8];
  const float* c3t = (const float*)d_in[9];
  const float* g1  = (const float*)d_in[10];
  const float* b1  = (const float*)d_in[11];
  const float* g2  = (const float*)d_in[12];
  const float* b2  = (const float*)d_in[13];
  const float* g3  = (const float*)d_in[14];
  const float* b3  = (const float*)d_in[15];

  float* ws = (float*)d_ws;
  const size_t FAST_NEED = 24255488ull * 4ull;   // ~97 MB (known-good layout)

  if (ws_size >= FAST_NEED) {
    // ---- fast MFMA path ----
    u16*   attnB = (u16*)ws;                         // 25,690,112 u16
    float* xT    = ws + 12845056;                    // 6,422,528 f (reused: L2 partial1 + out3)
    float* out1  = xT + 6422528;                     // 1,605,632 f
    float* out2  = out1 + 1605632;                   // 1,605,632 f
    bf16*  lutT1 = (bf16*)(out2 + 1605632);          // 1,048,576 u16
    bf16*  lutT2 = lutT1 + 1048576;
    bf16*  lutT3 = lutT2 + 1048576;
    float* part  = (float*)(lutT3 + 1048576);        // 200,704 f
    float* ss1   = part + 200704;                    // 512
    float* ss2   = ss1 + 512;                        // 512
    float* ss3   = ss2 + 512;                        // 2048
    float* out3  = xT;

    lutT_kernel<4096, 256><<<256, 256, 0, stream>>>(c1l, lutT1);
    lutT_kernel<4096, 256><<<256, 256, 0, stream>>>(c2l, lutT2);
    lutT_kernel<1024, 1024><<<256, 256, 0, stream>>>(c3l, lutT3);
    xT_kernel<<<512, 256, 0, stream>>>(x, xT);

    // layer 1: split-K2 partials -> out1, out2; add into out1
    attn1_kernel<<<3584, 256, 0, stream>>>(xT, c1c, c1t, attnB);
    gemm_kernel<4096, 4, 2><<<784, 256, 0, stream>>>(attnB, (const u16*)lutT1, out1, out2);
    add_kernel<<<1568, 256, 0, stream>>>(out1, out2);
    bnpart_kernel<256><<<98, 256, 0, stream>>>(out1, part);
    bnfin_kernel<256><<<1, 256, 0, stream>>>(part, g1, b1, ss1);

    // layer 2: partials -> out2, xT (dead after attn1; consumed by add before gemm3)
    attn2_kernel<<<3584, 256, 0, stream>>>(out1, ss1, c2c, c2t, attnB);
    gemm_kernel<4096, 4, 2><<<784, 256, 0, stream>>>(attnB, (const u16*)lutT2, out2, xT);
    add_kernel<<<1568, 256, 0, stream>>>(out2, xT);
    bnpart_kernel<256><<<98, 256, 0, stream>>>(out2, part);
    bnfin_kernel<256><<<1, 256, 0, stream>>>(part, g2, b2, ss2);

    // layer 3: no split (1568 blocks already)
    attn3_kernel<<<392, 256, 0, stream>>>(out2, ss2, c3c, c3t, (bf16*)attnB);
    gemm_kernel<1024, 16, 1><<<1568, 256, 0, stream>>>(attnB, (const u16*)lutT3, out3, out3);
    bnpart_kernel<1024><<<98, 256, 0, stream>>>(out3, part);
    bnfin_kernel<1024><<<4, 256, 0, stream>>>(part, g3, b3, ss3);

    tfinal_kernel<<<512, 256, 0, stream>>>(out3, ss3, x, (float*)d_out);
  } else {
    // ---- fallback (round-2 proven path) ----
    float* out3 = (float*)d_out;
    float* out1 = ws;
    float* out2 = out1 + 32 * 256 * 196;
    float* ss1  = out2 + 32 * 256 * 196;
    float* ss2  = ss1 + 512;
    float* ss3  = ss2 + 512;

    amm1x1_kernel<1024, 256, false><<<448, 256, 0, stream>>>(x, nullptr, c1c, c1l, c1t, out1);
    bnstats_kernel<256><<<256, 256, 0, stream>>>(out1, g1, b1, ss1);
    amm3x3_kernel<<<448, 256, 0, stream>>>(out1, ss1, c2c, c2l, c2t, out2);
    bnstats_kernel<256><<<256, 256, 0, stream>>>(out2, g2, b2, ss2);
    amm1x1_kernel<256, 1024, true><<<448, 256, 0, stream>>>(out2, ss2, c3c, c3l, c3t, out3);
    bnstats_kernel<1024><<<1024, 256, 0, stream>>>(out3, g3, b3, ss3);
    final_old_kernel<<<2048, 256, 0, stream>>>(out3, ss3, x);
  }
}

// Round 8
// 349.262 us; speedup vs baseline: 1.0333x; 1.0333x over previous
//
#include <hip/hip_runtime.h>
#include <hip/hip_bf16.h>

#define EPSV 1e-5f

typedef unsigned short u16;
typedef __attribute__((ext_vector_type(8))) short short8;
typedef __attribute__((ext_vector_type(4))) float f32x4;
typedef __hip_bfloat16 bf16;

__device__ __forceinline__ unsigned int pack2(float a, float b) {
  bf16 ha = __float2bfloat16(a), hb = __float2bfloat16(b);
  u16 ua, ub;
  __builtin_memcpy(&ua, &ha, 2);
  __builtin_memcpy(&ub, &hb, 2);
  return (unsigned int)ua | ((unsigned int)ub << 16);
}

// ============================================================================
// FAST PATH (MFMA) — position-major intermediates [M=6272, C]
// ============================================================================

// ---- transpose-convert lut [K,N] fp32 -> lutT [N,K] bf16 ----
template<int K, int N>
__global__ __launch_bounds__(256) void lutT_kernel(const float* __restrict__ in,
                                                   bf16* __restrict__ out)
{
  __shared__ float t[64][65];
  const int bk = blockIdx.x % (K / 64), bn = blockIdx.x / (K / 64);
  const int k0 = bk * 64, n0 = bn * 64;
  for (int idx = threadIdx.x; idx < 4096; idx += 256) {
    int r = idx >> 6, c = idx & 63;
    t[r][c] = in[(size_t)(k0 + r) * N + n0 + c];
  }
  __syncthreads();
  for (int idx = threadIdx.x; idx < 4096; idx += 256) {
    int r = idx >> 6, c = idx & 63;
    out[(size_t)(n0 + r) * K + k0 + c] = __float2bfloat16(t[c][r]);
  }
}

// ---- transpose x [B,1024,196] -> xT [6272,1024] fp32 ----
__global__ __launch_bounds__(256) void xT_kernel(const float* __restrict__ x,
                                                 float* __restrict__ xT)
{
  __shared__ float t[64 * 199];
  const int b = blockIdx.x >> 4, c0 = (blockIdx.x & 15) * 64;
  for (int idx = threadIdx.x; idx < 64 * 196; idx += 256) {
    int ci = idx / 196, p = idx - ci * 196;
    t[ci * 199 + p] = x[(size_t)(b * 1024 + c0 + ci) * 196 + p];
  }
  __syncthreads();
  for (int idx = threadIdx.x; idx < 196 * 64; idx += 256) {
    int p = idx >> 6, ci = idx & 63;
    xT[(size_t)(b * 196 + p) * 1024 + c0 + ci] = t[ci * 199 + p];
  }
}

// ---- attn layer 1 (R7): block = row x 32-cb group; f4 LDS reads ----
__global__ __launch_bounds__(256) void attn1_kernel(const float* __restrict__ xT,
    const float* __restrict__ cent, const float* __restrict__ invt,
    u16* __restrict__ attn)
{
  __shared__ float vs[14 * 128];
  __shared__ float cs[32 * 68];
  const int tid = threadIdx.x;
  const int row = blockIdx.x >> 3, cg = blockIdx.x & 7;
  const int m0 = row * 14;
  for (int idx = tid; idx < 448; idx += 256) {
    int p = idx >> 5, c4 = idx & 31;
    *(float4*)&vs[p * 128 + c4 * 4] =
        *(const float4*)&xT[(size_t)(m0 + p) * 1024 + cg * 128 + c4 * 4];
  }
  for (int idx = tid; idx < 512; idx += 256) {
    int cb = idx >> 4, kk = idx & 15;
    *(float4*)&cs[cb * 68 + kk * 4] =
        *(const float4*)&cent[(size_t)(cg * 32 + cb) * 64 + kk * 4];
  }
  __syncthreads();
  const float it = invt[0];
  const int cb = tid & 31, pq = tid >> 5;
  const int np = (pq < 6) ? 2 : 1;
  float4 v[2];
  v[0] = *(const float4*)&vs[pq * 128 + cb * 4];
  if (np > 1) v[1] = *(const float4*)&vs[(8 + pq) * 128 + cb * 4];
  float s[2][16];
  #pragma unroll
  for (int k = 0; k < 16; k++) {
    const float4 c = *(const float4*)&cs[cb * 68 + k * 4];
    const float cn = c.x * c.x + c.y * c.y + c.z * c.z + c.w * c.w;
    #pragma unroll
    for (int i = 0; i < 2; i++) if (i < np) {
      float d = v[i].x * c.x + v[i].y * c.y + v[i].z * c.z + v[i].w * c.w;
      s[i][k] = it * (2.f * d - cn);
    }
  }
  #pragma unroll
  for (int i = 0; i < 2; i++) if (i < np) {
    float mx = -3e38f;
    #pragma unroll
    for (int k = 0; k < 16; k++) mx = fmaxf(mx, s[i][k]);
    float sum = 0.f;
    #pragma unroll
    for (int k = 0; k < 16; k++) { float e = __expf(s[i][k] - mx); s[i][k] = e; sum += e; }
    const float r = 1.f / sum;
    uint4 w0, w1;
    w0.x = pack2(s[i][0] * r,  s[i][1] * r);  w0.y = pack2(s[i][2] * r,  s[i][3] * r);
    w0.z = pack2(s[i][4] * r,  s[i][5] * r);  w0.w = pack2(s[i][6] * r,  s[i][7] * r);
    w1.x = pack2(s[i][8] * r,  s[i][9] * r);  w1.y = pack2(s[i][10] * r, s[i][11] * r);
    w1.z = pack2(s[i][12] * r, s[i][13] * r); w1.w = pack2(s[i][14] * r, s[i][15] * r);
    uint4* dst = (uint4*)(attn + (size_t)(m0 + i * 8 + pq) * 4096 + (cg * 32 + cb) * 16);
    dst[0] = w0; dst[1] = w1;
  }
}

// ---- attn layer 2 (3x3) v3: 2 rows (28 pos) x 32 cb per block; grid 1792.
// Centroids in padded f4 layout [cb][k*12+j], stride 196 -> 2xb128+1xb32 per k.
__global__ __launch_bounds__(256) void attn2_kernel(const float* __restrict__ out1,
    const float* __restrict__ ss, const float* __restrict__ cent,
    const float* __restrict__ invt, u16* __restrict__ attn)
{
  __shared__ float vs[4 * 16 * 32];             // 8 KB [dyy][x1][c]; x1 0,15 = pad
  __shared__ __align__(16) float cs[32 * 196];  // 24.5 KB [cb][k*12+j], j<9
  const int tid = threadIdx.x;
  const int rp = blockIdx.x >> 3, cg = blockIdx.x & 7;
  const int b = rp / 7, y0 = (rp % 7) * 2, m0 = rp * 28;
  // stage patches: rows y0-1 .. y0+2
  for (int e = tid; e < 2048; e += 256) {
    int c = e & 31, x1 = (e >> 5) & 15, dyy = e >> 9;
    int yy = y0 + dyy - 1, xx = x1 - 1;
    float v = 0.f;
    int ch = cg * 32 + c;
    if (yy >= 0 && yy < 14 && xx >= 0 && xx < 14) {
      float val = out1[(size_t)((b * 14 + yy) * 14 + xx) * 256 + ch];
      v = fmaxf(val * ss[ch] + ss[256 + ch], 0.f);   // pad AFTER bn+relu
    }
    vs[e] = v;
  }
  // stage centroids: f4 global loads, scatter to padded layout
  for (int idx = tid; idx < 1152; idx += 256) {
    int cb = idx / 36, f4i = idx - cb * 36;
    float4 w = *(const float4*)&cent[(size_t)(cg * 32 + cb) * 144 + f4i * 4];
    int j0 = f4i * 4;
    #pragma unroll
    for (int t = 0; t < 4; t++) {
      int j = j0 + t, k = j / 9, jj = j - k * 9;
      cs[cb * 196 + k * 12 + jj] = ((const float*)&w)[t];
    }
  }
  __syncthreads();
  const float it = invt[0];
  const int cb = tid & 31, pq = tid >> 5;       // 8 pos-slots
  const int np = (pq < 4) ? 4 : 3;              // p = i*8 + pq < 28
  float v[4][9];
  #pragma unroll
  for (int i = 0; i < 4; i++) if (i < np) {
    const int p = i * 8 + pq;
    const int r = p / 14, xc = p - r * 14;
    #pragma unroll
    for (int dy = 0; dy < 3; dy++)
      #pragma unroll
      for (int dx = 0; dx < 3; dx++)
        v[i][dy * 3 + dx] = vs[((r + dy) * 16 + xc + dx) * 32 + cb];
  }
  float s[4][16];
  #pragma unroll
  for (int k = 0; k < 16; k++) {
    const float* ck = &cs[cb * 196 + k * 12];
    const float4 ca = *(const float4*)ck;
    const float4 cbv = *(const float4*)(ck + 4);
    const float c8 = ck[8];
    float c9[9] = {ca.x, ca.y, ca.z, ca.w, cbv.x, cbv.y, cbv.z, cbv.w, c8};
    float cn = 0.f;
    #pragma unroll
    for (int j = 0; j < 9; j++) cn = fmaf(c9[j], c9[j], cn);
    #pragma unroll
    for (int i = 0; i < 4; i++) if (i < np) {
      float d = 0.f;
      #pragma unroll
      for (int j = 0; j < 9; j++) d = fmaf(c9[j], v[i][j], d);
      s[i][k] = it * (2.f * d - cn);
    }
  }
  #pragma unroll
  for (int i = 0; i < 4; i++) if (i < np) {
    float mx = -3e38f;
    #pragma unroll
    for (int k = 0; k < 16; k++) mx = fmaxf(mx, s[i][k]);
    float sum = 0.f;
    #pragma unroll
    for (int k = 0; k < 16; k++) { float e = __expf(s[i][k] - mx); s[i][k] = e; sum += e; }
    const float r = 1.f / sum;
    uint4 w0, w1;
    w0.x = pack2(s[i][0] * r,  s[i][1] * r);  w0.y = pack2(s[i][2] * r,  s[i][3] * r);
    w0.z = pack2(s[i][4] * r,  s[i][5] * r);  w0.w = pack2(s[i][6] * r,  s[i][7] * r);
    w1.x = pack2(s[i][8] * r,  s[i][9] * r);  w1.y = pack2(s[i][10] * r, s[i][11] * r);
    w1.z = pack2(s[i][12] * r, s[i][13] * r); w1.w = pack2(s[i][14] * r, s[i][15] * r);
    uint4* dst = (uint4*)(attn + (size_t)(m0 + i * 8 + pq) * 4096 + (cg * 32 + cb) * 16);
    dst[0] = w0; dst[1] = w1;
  }
}

// ---- attn layer 3 (R3-proven) ----
__global__ __launch_bounds__(256) void attn3_kernel(const float* __restrict__ out2,
    const float* __restrict__ ss, const float* __restrict__ cent,
    const float* __restrict__ invt, bf16* __restrict__ attn)
{
  const int t = threadIdx.x;
  const int cb = t & 63, ml = t >> 6;
  const int m0 = blockIdx.x * 16;
  const float it = invt[0];
  float4 cv[16]; float cn[16];
  const float4* cc = (const float4*)(cent + cb * 64);
  #pragma unroll
  for (int k = 0; k < 16; k++) {
    cv[k] = cc[k];
    cn[k] = cv[k].x * cv[k].x + cv[k].y * cv[k].y + cv[k].z * cv[k].z + cv[k].w * cv[k].w;
  }
  const float4 scv = *(const float4*)(ss + cb * 4);
  const float4 shv = *(const float4*)(ss + 256 + cb * 4);
  for (int g = 0; g < 4; g++) {
    const int m = m0 + g * 4 + ml;
    float4 xv = *(const float4*)(out2 + (size_t)m * 256 + cb * 4);
    float4 v;
    v.x = fmaxf(xv.x * scv.x + shv.x, 0.f);
    v.y = fmaxf(xv.y * scv.y + shv.y, 0.f);
    v.z = fmaxf(xv.z * scv.z + shv.z, 0.f);
    v.w = fmaxf(xv.w * scv.w + shv.w, 0.f);
    float s[16], mx = -3e38f;
    #pragma unroll
    for (int k = 0; k < 16; k++) {
      float d = v.x * cv[k].x + v.y * cv[k].y + v.z * cv[k].z + v.w * cv[k].w;
      s[k] = it * (2.f * d - cn[k]);
      mx = fmaxf(mx, s[k]);
    }
    float sum = 0.f;
    #pragma unroll
    for (int k = 0; k < 16; k++) { float e = __expf(s[k] - mx); s[k] = e; sum += e; }
    float r = 1.f / sum;
    #pragma unroll
    for (int k = 0; k < 16; k++)
      attn[(size_t)m * 1024 + cb * 16 + k] = __float2bfloat16(s[k] * r);
  }
}

// ---- MFMA fragment compute on one 64x64 LDS tile pair ----
__device__ __forceinline__ void gemm_tile_compute(const u16* __restrict__ Abuf,
    const u16* __restrict__ Bbuf, int lane, int wm, int wn, f32x4 acc[2][2])
{
  #pragma unroll
  for (int ks = 0; ks < 2; ks++) {
    short8 a[2], b[2];
    #pragma unroll
    for (int f = 0; f < 2; f++) {
      const int ra = wm * 32 + f * 16 + (lane & 15);
      const int ja = (ks * 4 + (lane >> 4)) ^ (ra & 7);
      a[f] = *(const short8*)(Abuf + ra * 64 + ja * 8);
      const int rb = wn * 32 + f * 16 + (lane & 15);
      const int jb = (ks * 4 + (lane >> 4)) ^ (rb & 7);
      b[f] = *(const short8*)(Bbuf + rb * 64 + jb * 8);
    }
    #pragma unroll
    for (int fm = 0; fm < 2; fm++)
      #pragma unroll
      for (int fn = 0; fn < 2; fn++)
        acc[fm][fn] = __builtin_amdgcn_mfma_f32_16x16x32_bf16(a[fm], b[fn], acc[fm][fn], 0, 0, 0);
  }
}

// ---- bf16 MFMA GEMM (R6-proven): 64x64 tile, BK=64, dbuf LDS + reg prefetch,
//      optional split-K ----
template<int KDIM, int NTILES, int KSLICES>
__global__ __launch_bounds__(256) void gemm_kernel(const u16* __restrict__ A,
    const u16* __restrict__ Bt, float* __restrict__ C0, float* __restrict__ C1)
{
  constexpr int NDIM = NTILES * 64;
  __shared__ __align__(16) u16 Asm[2][64 * 64];
  __shared__ __align__(16) u16 Bsm[2][64 * 64];
  const int tid = threadIdx.x;
  const int nt = blockIdx.x % NTILES;
  const int mt = (blockIdx.x / NTILES) % 98;
  const int sl = blockIdx.x / (NTILES * 98);
  float* __restrict__ C = (KSLICES == 2 && sl == 1) ? C1 : C0;
  const int kbeg = sl * (KDIM / KSLICES), kend = kbeg + KDIM / KSLICES;
  const int m0 = mt * 64, n0 = nt * 64;
  const int lane = tid & 63;
  const int wm = (tid >> 7) & 1, wn = (tid >> 6) & 1;

  int rowi[2], jsi[2], jgi[2];
  #pragma unroll
  for (int i = 0; i < 2; i++) {
    const int L = tid + 256 * i;
    rowi[i] = L >> 3; jsi[i] = L & 7; jgi[i] = jsi[i] ^ (rowi[i] & 7);
  }

  f32x4 acc[2][2];
  const f32x4 zero = {0.f, 0.f, 0.f, 0.f};
  acc[0][0] = zero; acc[0][1] = zero; acc[1][0] = zero; acc[1][1] = zero;

  int4 av[2], bv[2];
  #pragma unroll
  for (int i = 0; i < 2; i++) {
    av[i] = *(const int4*)(A + (size_t)(m0 + rowi[i]) * KDIM + kbeg + jsi[i] * 8);
    bv[i] = *(const int4*)(Bt + (size_t)(n0 + rowi[i]) * KDIM + kbeg + jsi[i] * 8);
  }
  #pragma unroll
  for (int i = 0; i < 2; i++) {
    *(int4*)(&Asm[0][rowi[i] * 64 + jgi[i] * 8]) = av[i];
    *(int4*)(&Bsm[0][rowi[i] * 64 + jgi[i] * 8]) = bv[i];
  }
  __syncthreads();

  int cur = 0;
  for (int kb = kbeg + 64; kb < kend; kb += 64) {
    #pragma unroll
    for (int i = 0; i < 2; i++) {
      av[i] = *(const int4*)(A + (size_t)(m0 + rowi[i]) * KDIM + kb + jsi[i] * 8);
      bv[i] = *(const int4*)(Bt + (size_t)(n0 + rowi[i]) * KDIM + kb + jsi[i] * 8);
    }
    gemm_tile_compute(Asm[cur], Bsm[cur], lane, wm, wn, acc);
    #pragma unroll
    for (int i = 0; i < 2; i++) {
      *(int4*)(&Asm[cur ^ 1][rowi[i] * 64 + jgi[i] * 8]) = av[i];
      *(int4*)(&Bsm[cur ^ 1][rowi[i] * 64 + jgi[i] * 8]) = bv[i];
    }
    __syncthreads();
    cur ^= 1;
  }
  gemm_tile_compute(Asm[cur], Bsm[cur], lane, wm, wn, acc);

  #pragma unroll
  for (int fm = 0; fm < 2; fm++)
    #pragma unroll
    for (int fn = 0; fn < 2; fn++) {
      const int col = n0 + wn * 32 + fn * 16 + (lane & 15);
      const int rbase = m0 + wm * 32 + fm * 16 + (lane >> 4) * 4;
      #pragma unroll
      for (int r = 0; r < 4; r++)
        C[(size_t)(rbase + r) * NDIM + col] = acc[fm][fn][r];
    }
}

// ---- add partials: dst += src (1,605,632 floats as float4) ----
__global__ __launch_bounds__(256) void add_kernel(float* __restrict__ dst,
                                                  const float* __restrict__ src)
{
  const int idx = blockIdx.x * 256 + threadIdx.x;
  float4 a = ((const float4*)dst)[idx];
  float4 b = ((const float4*)src)[idx];
  a.x += b.x; a.y += b.y; a.z += b.z; a.w += b.w;
  ((float4*)dst)[idx] = a;
}

// ---- BN stats, stage 1: 64-row partial sums ----
template<int CH>
__global__ __launch_bounds__(256) void bnpart_kernel(const float* __restrict__ buf,
                                                     float* __restrict__ part)
{
  constexpr int PC = CH / 256;
  const int t = threadIdx.x, m0 = blockIdx.x * 64;
  float s[PC], s2[PC];
  #pragma unroll
  for (int j = 0; j < PC; j++) { s[j] = 0.f; s2[j] = 0.f; }
  for (int i = 0; i < 64; i++) {
    const float* row = buf + (size_t)(m0 + i) * CH;
    #pragma unroll
    for (int j = 0; j < PC; j++) {
      float v = row[t + j * 256];
      s[j] += v; s2[j] = fmaf(v, v, s2[j]);
    }
  }
  #pragma unroll
  for (int j = 0; j < PC; j++) {
    part[(size_t)blockIdx.x * (2 * CH) + t + j * 256] = s[j];
    part[(size_t)blockIdx.x * (2 * CH) + CH + t + j * 256] = s2[j];
  }
}

// ---- BN stats, stage 2 ----
template<int CH>
__global__ __launch_bounds__(256) void bnfin_kernel(const float* __restrict__ part,
    const float* __restrict__ g, const float* __restrict__ bb, float* __restrict__ ss)
{
  const int c = blockIdx.x * 256 + threadIdx.x;
  float S = 0.f, S2 = 0.f;
  for (int i = 0; i < 98; i++) {
    S += part[(size_t)i * (2 * CH) + c];
    S2 += part[(size_t)i * (2 * CH) + CH + c];
  }
  float mean = S * (1.f / 6272.f);
  float var = S2 * (1.f / 6272.f) - mean * mean;
  float sc = g[c] * rsqrtf(var + EPSV);
  ss[c] = sc;
  ss[CH + c] = bb[c] - mean * sc;
}

// ---- final: bn3 + transpose to channel-major + identity + relu ----
__global__ __launch_bounds__(256) void tfinal_kernel(const float* __restrict__ out3,
    const float* __restrict__ ss, const float* __restrict__ x, float* __restrict__ out)
{
  __shared__ float t[64 * 199];
  const int b = blockIdx.x >> 4, n0 = (blockIdx.x & 15) * 64;
  for (int idx = threadIdx.x; idx < 196 * 64; idx += 256) {
    int p = idx >> 6, ni = idx & 63;
    float v = out3[(size_t)(b * 196 + p) * 1024 + n0 + ni] * ss[n0 + ni] + ss[1024 + n0 + ni];
    t[ni * 199 + p] = v;
  }
  __syncthreads();
  for (int idx = threadIdx.x; idx < 64 * 196; idx += 256) {
    int ni = idx / 196, p = idx - ni * 196;
    size_t o = (size_t)(b * 1024 + n0 + ni) * 196 + p;
    out[o] = fmaxf(t[ni * 199 + p] + x[o], 0.f);
  }
}

// ============================================================================
// FALLBACK PATH (round-2 proven kernels, used only if ws_size is too small)
// ============================================================================

template<int CIN, int OUT, bool APPLY_BN>
__global__ __launch_bounds__(256) void amm1x1_kernel(
    const float* __restrict__ xin, const float* __restrict__ ss,
    const float* __restrict__ cent, const float* __restrict__ lut,
    const float* __restrict__ invt, float* __restrict__ outbuf)
{
  constexpr int NCB = CIN / 4;
  constexpr int NO = OUT / 256;
  __shared__ float vsm[CIN * 14];
  __shared__ __align__(16) float attn_sm[14 * 16];
  const int tid = threadIdx.x;
  const int b = blockIdx.x / 14, y = blockIdx.x % 14;
  const int rowbase = y * 14;
  for (int e = tid; e < CIN * 14; e += 256) {
    int c = e / 14, xc = e - c * 14;
    float v = xin[(b * CIN + c) * 196 + rowbase + xc];
    if (APPLY_BN) v = fmaxf(v * ss[c] + ss[CIN + c], 0.f);
    vsm[e] = v;
  }
  __syncthreads();
  float acc[14 * NO];
  #pragma unroll
  for (int i = 0; i < 14 * NO; i++) acc[i] = 0.f;
  const float it = invt[0];
  const int p_ = tid >> 4, k_ = tid & 15;
  for (int cb = 0; cb < NCB; ++cb) {
    if (tid < 224) {
      const float* cc = cent + (cb * 16 + k_) * 4;
      float s = 0.f;
      #pragma unroll
      for (int si = 0; si < 4; si++) {
        float cv = cc[si];
        float vv = vsm[(cb * 4 + si) * 14 + p_];
        s = fmaf(cv, 2.f * vv - cv, s);
      }
      s *= it;
      float m = s;
      #pragma unroll
      for (int off = 8; off; off >>= 1) m = fmaxf(m, __shfl_xor(m, off, 16));
      float e = __expf(s - m);
      float sum = e;
      #pragma unroll
      for (int off = 8; off; off >>= 1) sum += __shfl_xor(sum, off, 16);
      attn_sm[p_ * 16 + k_] = e / sum;
    }
    __syncthreads();
    float lv[NO][16];
    #pragma unroll
    for (int j = 0; j < NO; j++)
      #pragma unroll
      for (int k = 0; k < 16; k++)
        lv[j][k] = lut[(cb * 16 + k) * OUT + j * 256 + tid];
    const float4* a4 = (const float4*)attn_sm;
    #pragma unroll
    for (int p = 0; p < 14; p++) {
      float4 q0 = a4[p*4+0], q1 = a4[p*4+1], q2 = a4[p*4+2], q3 = a4[p*4+3];
      float av[16] = {q0.x,q0.y,q0.z,q0.w, q1.x,q1.y,q1.z,q1.w,
                      q2.x,q2.y,q2.z,q2.w, q3.x,q3.y,q3.z,q3.w};
      #pragma unroll
      for (int j = 0; j < NO; j++) {
        float s = acc[p * NO + j];
        #pragma unroll
        for (int k = 0; k < 16; k++) s = fmaf(av[k], lv[j][k], s);
        acc[p * NO + j] = s;
      }
    }
    __syncthreads();
  }
  #pragma unroll
  for (int j = 0; j < NO; j++) {
    int o = j * 256 + tid;
    #pragma unroll
    for (int p = 0; p < 14; p++)
      outbuf[(b * OUT + o) * 196 + rowbase + p] = acc[p * NO + j];
  }
}

__global__ __launch_bounds__(256) void amm3x3_kernel(
    const float* __restrict__ xin, const float* __restrict__ ss,
    const float* __restrict__ cent, const float* __restrict__ lut,
    const float* __restrict__ invt, float* __restrict__ outbuf)
{
  __shared__ float vsm[256 * 3 * 16];
  __shared__ __align__(16) float attn_sm[14 * 16];
  const int tid = threadIdx.x;
  const int b = blockIdx.x / 14, y = blockIdx.x % 14;
  for (int e = tid; e < 256 * 3 * 16; e += 256) {
    int c = e / 48, rem = e - c * 48, i = rem >> 4, col = rem & 15;
    int yy = y + i - 1, xx = col - 1;
    float v = 0.f;
    if (yy >= 0 && yy < 14 && xx >= 0 && xx < 14) {
      v = xin[(b * 256 + c) * 196 + yy * 14 + xx];
      v = fmaxf(v * ss[c] + ss[256 + c], 0.f);
    }
    vsm[e] = v;
  }
  __syncthreads();
  float acc[14];
  #pragma unroll
  for (int i = 0; i < 14; i++) acc[i] = 0.f;
  const float it = invt[0];
  const int p_ = tid >> 4, k_ = tid & 15;
  for (int cb = 0; cb < 256; ++cb) {
    if (tid < 224) {
      const float* cc = cent + (cb * 16 + k_) * 9;
      float s = 0.f;
      #pragma unroll
      for (int i = 0; i < 3; i++)
        #pragma unroll
        for (int j = 0; j < 3; j++) {
          float cv = cc[i * 3 + j];
          float vv = vsm[(cb * 3 + i) * 16 + p_ + j];
          s = fmaf(cv, 2.f * vv - cv, s);
        }
      s *= it;
      float m = s;
      #pragma unroll
      for (int off = 8; off; off >>= 1) m = fmaxf(m, __shfl_xor(m, off, 16));
      float e = __expf(s - m);
      float sum = e;
      #pragma unroll
      for (int off = 8; off; off >>= 1) sum += __shfl_xor(sum, off, 16);
      attn_sm[p_ * 16 + k_] = e / sum;
    }
    __syncthreads();
    float lv[16];
    #pragma unroll
    for (int k = 0; k < 16; k++) lv[k] = lut[(cb * 16 + k) * 256 + tid];
    const float4* a4 = (const float4*)attn_sm;
    #pragma unroll
    for (int p = 0; p < 14; p++) {
      float4 q0 = a4[p*4+0], q1 = a4[p*4+1], q2 = a4[p*4+2], q3 = a4[p*4+3];
      float av[16] = {q0.x,q0.y,q0.z,q0.w, q1.x,q1.y,q1.z,q1.w,
                      q2.x,q2.y,q2.z,q2.w, q3.x,q3.y,q3.z,q3.w};
      float s = acc[p];
      #pragma unroll
      for (int k = 0; k < 16; k++) s = fmaf(av[k], lv[k], s);
      acc[p] = s;
    }
    __syncthreads();
  }
  #pragma unroll
  for (int p = 0; p < 14; p++)
    outbuf[(b * 256 + tid) * 196 + y * 14 + p] = acc[p];
}

template<int CH>
__global__ __launch_bounds__(256) void bnstats_kernel(const float* __restrict__ buf,
    const float* __restrict__ g, const float* __restrict__ bb, float* __restrict__ ss)
{
  const int c = blockIdx.x, tid = threadIdx.x;
  float s = 0.f, s2 = 0.f;
  for (int e = tid; e < 32 * 196; e += 256) {
    int bi = e / 196, l = e - bi * 196;
    float v = buf[(bi * CH + c) * 196 + l];
    s += v; s2 = fmaf(v, v, s2);
  }
  #pragma unroll
  for (int off = 32; off; off >>= 1) { s += __shfl_down(s, off); s2 += __shfl_down(s2, off); }
  __shared__ float red[8];
  int w = tid >> 6;
  if ((tid & 63) == 0) { red[w] = s; red[4 + w] = s2; }
  __syncthreads();
  if (tid == 0) {
    float S  = red[0] + red[1] + red[2] + red[3];
    float S2 = red[4] + red[5] + red[6] + red[7];
    float mean = S * (1.f / 6272.f);
    float var  = S2 * (1.f / 6272.f) - mean * mean;
    float sc = g[c] * rsqrtf(var + EPSV);
    ss[c] = sc;
    ss[CH + c] = bb[c] - mean * sc;
  }
}

__global__ __launch_bounds__(256) void final_old_kernel(float* __restrict__ out3,
    const float* __restrict__ ss, const float* __restrict__ x)
{
  const int total = 32 * 1024 * 196;
  for (int idx = blockIdx.x * 256 + threadIdx.x; idx < total; idx += gridDim.x * 256) {
    int c = (idx / 196) & 1023;
    float v = out3[idx] * ss[c] + ss[1024 + c] + x[idx];
    out3[idx] = fmaxf(v, 0.f);
  }
}

// ============================================================================

extern "C" void kernel_launch(void* const* d_in, const int* in_sizes, int n_in,
                              void* d_out, int out_size, void* d_ws, size_t ws_size,
                              hipStream_t stream) {
  const float* x   = (const float*)d_in[0];
  const float* c1c = (const float*)d_in[1];
  const float* c1l = (const float*)d_in[2];
  const float* c1t = (const float*)d_in[3];
  const float* c2c = (const float*)d_in[4];
  const float* c2l = (const float*)d_in[5];
  const float* c2t = (const float*)d_in[6];
  const float* c3c = (const float*)d_in[7];
  const float* c3l = (const float*)d_in[8];
  const float* c3t = (const float*)d_in[9];
  const float* g1  = (const float*)d_in[10];
  const float* b1  = (const float*)d_in[11];
  const float* g2  = (const float*)d_in[12];
  const float* b2  = (const float*)d_in[13];
  const float* g3  = (const float*)d_in[14];
  const float* b3  = (const float*)d_in[15];

  float* ws = (float*)d_ws;
  const size_t FAST_NEED = 24255488ull * 4ull;   // ~97 MB (known-good layout)

  if (ws_size >= FAST_NEED) {
    // ---- fast MFMA path ----
    u16*   attnB = (u16*)ws;                         // 25,690,112 u16
    float* xT    = ws + 12845056;                    // 6,422,528 f (reused: L2 partial1 + out3)
    float* out1  = xT + 6422528;                     // 1,605,632 f
    float* out2  = out1 + 1605632;                   // 1,605,632 f
    bf16*  lutT1 = (bf16*)(out2 + 1605632);          // 1,048,576 u16
    bf16*  lutT2 = lutT1 + 1048576;
    bf16*  lutT3 = lutT2 + 1048576;
    float* part  = (float*)(lutT3 + 1048576);        // 200,704 f
    float* ss1   = part + 200704;                    // 512
    float* ss2   = ss1 + 512;                        // 512
    float* ss3   = ss2 + 512;                        // 2048
    float* out3  = xT;

    lutT_kernel<4096, 256><<<256, 256, 0, stream>>>(c1l, lutT1);
    lutT_kernel<4096, 256><<<256, 256, 0, stream>>>(c2l, lutT2);
    lutT_kernel<1024, 1024><<<256, 256, 0, stream>>>(c3l, lutT3);
    xT_kernel<<<512, 256, 0, stream>>>(x, xT);

    // layer 1: split-K2 partials -> out1, out2; add into out1
    attn1_kernel<<<3584, 256, 0, stream>>>(xT, c1c, c1t, attnB);
    gemm_kernel<4096, 4, 2><<<784, 256, 0, stream>>>(attnB, (const u16*)lutT1, out1, out2);
    add_kernel<<<1568, 256, 0, stream>>>(out1, out2);
    bnpart_kernel<256><<<98, 256, 0, stream>>>(out1, part);
    bnfin_kernel<256><<<1, 256, 0, stream>>>(part, g1, b1, ss1);

    // layer 2: partials -> out2, xT (dead after attn1; consumed by add before gemm3)
    attn2_kernel<<<1792, 256, 0, stream>>>(out1, ss1, c2c, c2t, attnB);
    gemm_kernel<4096, 4, 2><<<784, 256, 0, stream>>>(attnB, (const u16*)lutT2, out2, xT);
    add_kernel<<<1568, 256, 0, stream>>>(out2, xT);
    bnpart_kernel<256><<<98, 256, 0, stream>>>(out2, part);
    bnfin_kernel<256><<<1, 256, 0, stream>>>(part, g2, b2, ss2);

    // layer 3: no split (1568 blocks already)
    attn3_kernel<<<392, 256, 0, stream>>>(out2, ss2, c3c, c3t, (bf16*)attnB);
    gemm_kernel<1024, 16, 1><<<1568, 256, 0, stream>>>(attnB, (const u16*)lutT3, out3, out3);
    bnpart_kernel<1024><<<98, 256, 0, stream>>>(out3, part);
    bnfin_kernel<1024><<<4, 256, 0, stream>>>(part, g3, b3, ss3);

    tfinal_kernel<<<512, 256, 0, stream>>>(out3, ss3, x, (float*)d_out);
  } else {
    // ---- fallback (round-2 proven path) ----
    float* out3 = (float*)d_out;
    float* out1 = ws;
    float* out2 = out1 + 32 * 256 * 196;
    float* ss1  = out2 + 32 * 256 * 196;
    float* ss2  = ss1 + 512;
    float* ss3  = ss2 + 512;

    amm1x1_kernel<1024, 256, false><<<448, 256, 0, stream>>>(x, nullptr, c1c, c1l, c1t, out1);
    bnstats_kernel<256><<<256, 256, 0, stream>>>(out1, g1, b1, ss1);
    amm3x3_kernel<<<448, 256, 0, stream>>>(out1, ss1, c2c, c2l, c2t, out2);
    bnstats_kernel<256><<<256, 256, 0, stream>>>(out2, g2, b2, ss2);
    amm1x1_kernel<256, 1024, true><<<448, 256, 0, stream>>>(out2, ss2, c3c, c3l, c3t, out3);
    bnstats_kernel<1024><<<1024, 256, 0, stream>>>(out3, g3, b3, ss3);
    final_old_kernel<<<2048, 256, 0, stream>>>(out3, ss3, x);
  }
}